// Round 19
// baseline (155.504 us; speedup 1.0000x reference)
//
#include <hip/hip_runtime.h>
#include <hip/hip_bf16.h>

#define EMB 512
#define NSTK 32
#define NPNT 64
#define BSZ 32

typedef __attribute__((ext_vector_type(8))) _Float16 f16x8;
typedef __attribute__((ext_vector_type(4))) float f32x4;
typedef __attribute__((ext_vector_type(4))) unsigned short us4;
typedef __attribute__((ext_vector_type(8))) unsigned short us8;
typedef __attribute__((ext_vector_type(2))) float f32x2;

static __device__ __forceinline__ unsigned short f16bits(float x) {
    _Float16 h = (_Float16)x;
    return *reinterpret_cast<unsigned short*>(&h);
}

// async global->LDS DMA: dest = wave-uniform lds base + lane*16 (m104 semantics)
#define GLL(gsrc, ldst)                                                         \
    __builtin_amdgcn_global_load_lds(                                           \
        (const __attribute__((address_space(1))) void*)(gsrc),                  \
        (__attribute__((address_space(3))) void*)(ldst), 16, 0, 0)

#define SBAR() __builtin_amdgcn_s_barrier()

// ---------------------------------------------------------------------------
// Kernel AB (merged): blocks [0,512) convert Wk/Wg -> f16; blocks [512,768)
// run the fp32 qv GEMM.
// ---------------------------------------------------------------------------
__global__ __launch_bounds__(256)
void prep(const float* __restrict__ wk, const float* __restrict__ wg,
          _Float16* __restrict__ wkf, _Float16* __restrict__ wgf,
          const float* __restrict__ sparse,
          const float* __restrict__ Wq, const float* __restrict__ sq, const float* __restrict__ bq,
          const float* __restrict__ Wv, const float* __restrict__ sv, const float* __restrict__ bv,
          float* __restrict__ outq, float* __restrict__ outv) {
    if (blockIdx.x < 512) {
        int idx = blockIdx.x * blockDim.x + threadIdx.x;   // 0..131071
        const float* src;
        _Float16* dst;
        int k;
        if (idx < 65536) { src = wk; dst = wkf; k = idx; }
        else             { src = wg; dst = wgf; k = idx - 65536; }
        f32x4 v = *reinterpret_cast<const f32x4*>(src + (size_t)k * 4);
        us4 o;
#pragma unroll
        for (int e = 0; e < 4; ++e) o[e] = f16bits(v[e]);
        *reinterpret_cast<us4*>(dst + (size_t)k * 4) = o;
        return;
    }

    const int bid = blockIdx.x - 512;            // 0..255
    const int bx = bid & 15, by = (bid >> 4) & 7, bz = bid >> 7;
    const float* W  = (bz == 0) ? Wq : Wv;
    const float* sc = (bz == 0) ? sq : sv;
    const float* bi = (bz == 0) ? bq : bv;
    float* orow     = (bz == 0) ? outq : outv;

    __shared__ float Wt[64][33];
    __shared__ float St[32][65];

    const int m0 = bx * 64;
    const int o0 = by * 64;
    const int t  = threadIdx.x;
    const int ty = t >> 4, tx = t & 15;

    float acc[4][4] = {};

    for (int k0 = 0; k0 < 512; k0 += 32) {
        {
            int ol = t >> 2, kl = (t & 3) * 8;
            const float* p = W + (size_t)(o0 + ol) * 512 + k0 + kl;
            f32x4 v0 = *reinterpret_cast<const f32x4*>(p);
            f32x4 v1 = *reinterpret_cast<const f32x4*>(p + 4);
#pragma unroll
            for (int e = 0; e < 4; ++e) { Wt[ol][kl + e] = v0[e]; Wt[ol][kl + 4 + e] = v1[e]; }
        }
        {
            int kl = t >> 3, ml = (t & 7) * 8;
            int mm = m0 + ml;
            int bb = mm >> 5, iidx = mm & 31;
            const float* p = sparse + (size_t)bb * 16384 + (size_t)(k0 + kl) * 32 + iidx;
            f32x4 v0 = *reinterpret_cast<const f32x4*>(p);
            f32x4 v1 = *reinterpret_cast<const f32x4*>(p + 4);
#pragma unroll
            for (int e = 0; e < 4; ++e) { St[kl][ml + e] = v0[e]; St[kl][ml + 4 + e] = v1[e]; }
        }
        __syncthreads();
#pragma unroll
        for (int kk = 0; kk < 32; ++kk) {
            float av[4], bvv[4];
#pragma unroll
            for (int e = 0; e < 4; ++e) av[e]  = Wt[ty * 4 + e][kk];
#pragma unroll
            for (int e = 0; e < 4; ++e) bvv[e] = St[kk][tx * 4 + e];
#pragma unroll
            for (int a = 0; a < 4; ++a)
#pragma unroll
                for (int bb2 = 0; bb2 < 4; ++bb2) acc[a][bb2] += av[a] * bvv[bb2];
        }
        __syncthreads();
    }
#pragma unroll
    for (int ae = 0; ae < 4; ++ae) {
        int o = o0 + ty * 4 + ae;
        float s = sc[o], bb2 = bi[o];
#pragma unroll
        for (int be = 0; be < 4; ++be) {
            int mm = m0 + tx * 4 + be;
            float h = acc[ae][be] * s + bb2;
            h = (h >= 0.f) ? h : 0.2f * h;
            orow[(size_t)mm * 512 + o] = h;
        }
    }
}

// ---------------------------------------------------------------------------
// Kernel C: fused main. One WG (16 waves, 1024 thr) per (b,i).
// R18 structure + ONE-PASS softmax: exp against per-wave local max (no wait),
// publish (mw, sw) pairs, single barrier, fold exp(mw-M)/S into the final
// j-sum coefficient. One barrier + one cross-wave read loop removed.
// ---------------------------------------------------------------------------
__global__ __launch_bounds__(1024, 4)
void fused_attn(const float* __restrict__ dense,
                const _Float16* __restrict__ wkf,
                const _Float16* __restrict__ wgf,
                const float* __restrict__ wsq,
                const float* __restrict__ wsv,
                const float* __restrict__ sk, const float* __restrict__ bk,
                const float* __restrict__ sg, const float* __restrict__ bg,
                float* __restrict__ out) {
    __shared__ __align__(16) _Float16 XH[64][520];     // 66.5 KB, X -> D (f16)
    __shared__ __align__(16) _Float16 WP[2][512 * 32]; // 2 x 32 KB weight panels
    __shared__ __align__(16) float qrow[512];
    __shared__ __align__(16) float vrow[512];
    __shared__ f32x2 wred[16][64];                     // (mw, sw) pairs

    const int m   = blockIdx.x;        // 0..1023
    const int b   = m >> 5, ii = m & 31;
    const int tid = threadIdx.x;       // 0..1023
    const int w   = tid >> 6;          // wave 0..15
    const int l   = tid & 63;
    const int l15 = l & 15;
    const int lk  = l >> 4;            // 0..3

    const int tsw = ((l & 3) - ((l >> 3) & 3)) & 3;   // m173 source swizzle
    const int orl = l >> 2;
    const int aslot = (lk + ((l15 >> 1) & 3)) & 3;

    // ---- prologue: DMA Wk panel 0 into WP[0] (overlaps X staging)
#pragma unroll
    for (int ih = 0; ih < 2; ++ih) {
        const int o = w * 32 + ih * 16 + orl;
        GLL(wkf + (size_t)o * 512 + tsw * 8, &WP[0][(w * 32 + ih * 16) * 32]);
    }

    if (tid < 512) qrow[tid] = wsq[(size_t)m * 512 + tid];
    else           vrow[tid - 512] = wsv[(size_t)m * 512 + (tid - 512)];

    {   // stage X (f16): thread owns j-row l, c-block [w*32, +32)
        const float* src = dense + (size_t)b * 512 * 2048 + (size_t)ii * 64 + l;
#pragma unroll
        for (int e8 = 0; e8 < 4; ++e8) {
            const int c0 = w * 32 + e8 * 8;
            us8 pk;
#pragma unroll
            for (int e = 0; e < 8; ++e)
                pk[e] = f16bits(src[(size_t)(c0 + e) * 2048]);
            *reinterpret_cast<us8*>(&XH[l][c0]) = pk;
        }
    }
    __syncthreads();   // full drain: X staged + panel 0 resident (vmcnt=0)

    f32x4 acc[2][4];
#pragma unroll
    for (int fm = 0; fm < 2; ++fm)
#pragma unroll
        for (int fn = 0; fn < 4; ++fn) acc[fm][fn] = (f32x4){0.f, 0.f, 0.f, 0.f};

    f16x8 af[2], bf[4], afn[2], bfn[4];

    // GEMM1 pipeline prologue: issue panel 1; read frags(0)
#pragma unroll
    for (int ih = 0; ih < 2; ++ih) {
        const int o = w * 32 + ih * 16 + orl;
        GLL(wkf + (size_t)o * 512 + 32 + tsw * 8, &WP[1][(w * 32 + ih * 16) * 32]);
    }
#pragma unroll
    for (int fm = 0; fm < 2; ++fm)
        af[fm] = *reinterpret_cast<const f16x8*>(
            &WP[0][(w * 32 + fm * 16 + l15) * 32 + aslot * 8]);
#pragma unroll
    for (int fn = 0; fn < 4; ++fn)
        bf[fn] = *reinterpret_cast<const f16x8*>(&XH[fn * 16 + l15][lk * 8]);

    // ---- GEMM1: dn_k[o,j] = sum_c Wk[o,c] * X[c,j]
    for (int ks = 0; ks < 16; ++ks) {
        asm volatile("s_waitcnt lgkmcnt(0)" ::: "memory");
        {   // issue panel ks+2 into WP[ks&1] (14->wgf p0, 15->wgf p1)
            const _Float16* nxt = (ks <= 13) ? (wkf + (size_t)(ks + 2) * 32)
                                : (ks == 14) ? wgf : (wgf + 32);
#pragma unroll
            for (int ih = 0; ih < 2; ++ih) {
                const int o = w * 32 + ih * 16 + orl;
                GLL(nxt + (size_t)o * 512 + tsw * 8, &WP[ks & 1][(w * 32 + ih * 16) * 32]);
            }
        }
        asm volatile("s_waitcnt vmcnt(2)" ::: "memory");    // panel ks+1 landed
        {
            const _Float16* pbuf = WP[(ks + 1) & 1];
#pragma unroll
            for (int fm = 0; fm < 2; ++fm)
                afn[fm] = *reinterpret_cast<const f16x8*>(
                    pbuf + (w * 32 + fm * 16 + l15) * 32 + aslot * 8);
            if (ks < 15) {
#pragma unroll
                for (int fn = 0; fn < 4; ++fn)
                    bfn[fn] = *reinterpret_cast<const f16x8*>(
                        &XH[fn * 16 + l15][(ks + 1) * 32 + lk * 8]);
            }
        }
        __builtin_amdgcn_s_setprio(1);
#pragma unroll
        for (int fm = 0; fm < 2; ++fm)
#pragma unroll
            for (int fn = 0; fn < 4; ++fn)
                acc[fm][fn] = __builtin_amdgcn_mfma_f32_16x16x32_f16(af[fm], bf[fn], acc[fm][fn], 0, 0, 0);
        __builtin_amdgcn_s_setprio(0);
#pragma unroll
        for (int fm = 0; fm < 2; ++fm) af[fm] = afn[fm];
#pragma unroll
        for (int fn = 0; fn < 4; ++fn) bf[fn] = bfn[fn];
    }
    // af[] now holds GEMM2's af(0) (wgf panel 0, resident in WP[0])

    // RACE FIX: all waves done reading X from XH before D overwrites it
    asm volatile("s_waitcnt lgkmcnt(0)" ::: "memory");
    SBAR();

    // ---- epilogue1: d = q - lrelu(acc*sk+bk), f16, write D over XH
#pragma unroll
    for (int fm = 0; fm < 2; ++fm) {
        const int o0 = w * 32 + fm * 16 + lk * 4;
        f32x4 skv = *reinterpret_cast<const f32x4*>(sk + o0);
        f32x4 bkv = *reinterpret_cast<const f32x4*>(bk + o0);
        f32x4 qv4 = *reinterpret_cast<const f32x4*>(&qrow[o0]);
#pragma unroll
        for (int fn = 0; fn < 4; ++fn) {
            const int j = fn * 16 + l15;
            us4 pkh;
#pragma unroll
            for (int r = 0; r < 4; ++r) {
                float h = acc[fm][fn][r] * skv[r] + bkv[r];
                h = (h >= 0.f) ? h : 0.2f * h;
                pkh[r] = f16bits(qv4[r] - h);
            }
            *reinterpret_cast<us4*>(&XH[j][o0]) = pkh;
        }
    }
    asm volatile("s_waitcnt lgkmcnt(0)" ::: "memory");
    SBAR();   // D visible to all waves (wgf p1 DMA still in flight - OK)

    // ---- GEMM2: g[oo,j] = sum_o Wg[oo,o] * d[o,j]
#pragma unroll
    for (int fm = 0; fm < 2; ++fm)
#pragma unroll
        for (int fn = 0; fn < 4; ++fn) acc[fm][fn] = (f32x4){0.f, 0.f, 0.f, 0.f};

#pragma unroll
    for (int fn = 0; fn < 4; ++fn)
        bf[fn] = *reinterpret_cast<const f16x8*>(&XH[fn * 16 + l15][lk * 8]);

    for (int g = 0; g < 16; ++g) {
        asm volatile("s_waitcnt lgkmcnt(0)" ::: "memory");
        if (g <= 13) {
            const _Float16* nxt = wgf + (size_t)(g + 2) * 32;
#pragma unroll
            for (int ih = 0; ih < 2; ++ih) {
                const int o = w * 32 + ih * 16 + orl;
                GLL(nxt + (size_t)o * 512 + tsw * 8, &WP[g & 1][(w * 32 + ih * 16) * 32]);
            }
            asm volatile("s_waitcnt vmcnt(2)" ::: "memory");
        } else {
            asm volatile("s_waitcnt vmcnt(0)" ::: "memory");
        }
        if (g < 15) {
            const _Float16* pbuf = WP[(g + 1) & 1];
#pragma unroll
            for (int fm = 0; fm < 2; ++fm)
                afn[fm] = *reinterpret_cast<const f16x8*>(
                    pbuf + (w * 32 + fm * 16 + l15) * 32 + aslot * 8);
#pragma unroll
            for (int fn = 0; fn < 4; ++fn)
                bfn[fn] = *reinterpret_cast<const f16x8*>(
                    &XH[fn * 16 + l15][(g + 1) * 32 + lk * 8]);
        }
        __builtin_amdgcn_s_setprio(1);
#pragma unroll
        for (int fm = 0; fm < 2; ++fm)
#pragma unroll
            for (int fn = 0; fn < 4; ++fn)
                acc[fm][fn] = __builtin_amdgcn_mfma_f32_16x16x32_f16(af[fm], bf[fn], acc[fm][fn], 0, 0, 0);
        __builtin_amdgcn_s_setprio(0);
        if (g < 15) {
#pragma unroll
            for (int fm = 0; fm < 2; ++fm) af[fm] = afn[fm];
#pragma unroll
            for (int fn = 0; fn < 4; ++fn) bf[fn] = bfn[fn];
        }
    }

    // ---- epilogue2 + ONE-PASS softmax
    // g = lrelu(acc*sg+bg); per-wave local max mw[fn]; exp(v - mw) in place;
    // partial sum sw[fn]; publish (mw, sw); ONE barrier; combine.
#pragma unroll
    for (int fm = 0; fm < 2; ++fm) {
        const int o0 = w * 32 + fm * 16 + lk * 4;
        f32x4 sgv = *reinterpret_cast<const f32x4*>(sg + o0);
        f32x4 bgv = *reinterpret_cast<const f32x4*>(bg + o0);
#pragma unroll
        for (int fn = 0; fn < 4; ++fn)
#pragma unroll
            for (int r = 0; r < 4; ++r) {
                float h = acc[fm][fn][r] * sgv[r] + bgv[r];
                acc[fm][fn][r] = (h >= 0.f) ? h : 0.2f * h;
            }
    }

    float mw[4], sw[4];
#pragma unroll
    for (int fn = 0; fn < 4; ++fn) {
        float mx = -1e30f;
#pragma unroll
        for (int fm = 0; fm < 2; ++fm)
#pragma unroll
            for (int r = 0; r < 4; ++r) mx = fmaxf(mx, acc[fm][fn][r]);
        mx = fmaxf(mx, __shfl_xor(mx, 16, 64));
        mx = fmaxf(mx, __shfl_xor(mx, 32, 64));
        mw[fn] = mx;                      // wave-local max for column j
        float s = 0.f;
#pragma unroll
        for (int fm = 0; fm < 2; ++fm)
#pragma unroll
            for (int r = 0; r < 4; ++r) {
                float e = __expf(acc[fm][fn][r] - mx);
                acc[fm][fn][r] = e;
                s += e;
            }
        s += __shfl_xor(s, 16, 64);
        s += __shfl_xor(s, 32, 64);
        sw[fn] = s;
    }
    if (l < 16) {
#pragma unroll
        for (int fn = 0; fn < 4; ++fn)
            wred[w][fn * 16 + l] = (f32x2){mw[fn], sw[fn]};
    }
    __syncthreads();   // single softmax barrier

    // combine: M = max_w mw; S = sum_w sw*exp(mw-M); coef cf = exp(mw_own-M)/S
    float cf[4];
#pragma unroll
    for (int fn = 0; fn < 4; ++fn) {
        const int j = fn * 16 + l15;
        float M = wred[0][j][0];
#pragma unroll
        for (int ww = 1; ww < 16; ++ww) M = fmaxf(M, wred[ww][j][0]);
        float S = 0.f;
#pragma unroll
        for (int ww = 0; ww < 16; ++ww) {
            f32x2 p = wred[ww][j];
            S += p[1] * __expf(p[0] - M);
        }
        cf[fn] = __expf(mw[fn] - M) / S;
    }

    // ---- out[b,oo,i] = sp_v[oo] * sum_j cf[fn] * acc   (FP32 store)
#pragma unroll
    for (int fm = 0; fm < 2; ++fm) {
#pragma unroll
        for (int r = 0; r < 4; ++r) {
            float tsum = 0.f;
#pragma unroll
            for (int fn = 0; fn < 4; ++fn) tsum += acc[fm][fn][r] * cf[fn];
            tsum += __shfl_xor(tsum, 1, 64);
            tsum += __shfl_xor(tsum, 2, 64);
            tsum += __shfl_xor(tsum, 4, 64);
            tsum += __shfl_xor(tsum, 8, 64);
            if (l15 == 0) {
                int oo = w * 32 + fm * 16 + lk * 4 + r;
                out[((size_t)b * 512 + oo) * 32 + ii] = vrow[oo] * tsum;
            }
        }
    }
}

// ---------------------------------------------------------------------------
extern "C" void kernel_launch(void* const* d_in, const int* in_sizes, int n_in,
                              void* d_out, int out_size, void* d_ws, size_t ws_size,
                              hipStream_t stream) {
    const float* sparse = (const float*)d_in[0];
    const float* dense  = (const float*)d_in[1];
    const float* Wq = (const float*)d_in[2];
    const float* sq = (const float*)d_in[3];
    const float* bq = (const float*)d_in[4];
    const float* Wk = (const float*)d_in[5];
    const float* sk = (const float*)d_in[6];
    const float* bk = (const float*)d_in[7];
    const float* Wv = (const float*)d_in[8];
    const float* sv = (const float*)d_in[9];
    const float* bv = (const float*)d_in[10];
    const float* Wg = (const float*)d_in[11];
    const float* sg = (const float*)d_in[12];
    const float* bg = (const float*)d_in[13];
    float* out = (float*)d_out;

    // workspace: [sp_q f32 2MB][sp_v f32 2MB][Wk f16 512KB][Wg f16 512KB]
    float* wsq = (float*)d_ws;
    float* wsv = wsq + 1024 * 512;
    _Float16* wkf = (_Float16*)(wsv + 1024 * 512);
    _Float16* wgf = wkf + 512 * 512;

    prep<<<768, 256, 0, stream>>>(Wk, Wg, wkf, wgf,
                                  sparse, Wq, sq, bq, Wv, sv, bv, wsq, wsv);
    fused_attn<<<1024, 1024, 0, stream>>>(dense, wkf, wgf, wsq, wsv, sk, bk, sg, bg, out);
}

// Round 20
// 151.162 us; speedup vs baseline: 1.0287x; 1.0287x over previous
//
#include <hip/hip_runtime.h>
#include <hip/hip_bf16.h>

#define EMB 512
#define NSTK 32
#define NPNT 64
#define BSZ 32

typedef __attribute__((ext_vector_type(8))) _Float16 f16x8;
typedef __attribute__((ext_vector_type(4))) float f32x4;
typedef __attribute__((ext_vector_type(4))) unsigned short us4;
typedef __attribute__((ext_vector_type(8))) unsigned short us8;

static __device__ __forceinline__ unsigned short f16bits(float x) {
    _Float16 h = (_Float16)x;
    return *reinterpret_cast<unsigned short*>(&h);
}

// async global->LDS DMA: dest = wave-uniform lds base + lane*16 (m104 semantics)
#define GLL(gsrc, ldst)                                                         \
    __builtin_amdgcn_global_load_lds(                                           \
        (const __attribute__((address_space(1))) void*)(gsrc),                  \
        (__attribute__((address_space(3))) void*)(ldst), 16, 0, 0)

#define SBAR() __builtin_amdgcn_s_barrier()

// ---------------------------------------------------------------------------
// Kernel AB (merged): blocks [0,512) convert Wk/Wg -> f16; blocks [512,768)
// run the fp32 qv GEMM.
// ---------------------------------------------------------------------------
__global__ __launch_bounds__(256)
void prep(const float* __restrict__ wk, const float* __restrict__ wg,
          _Float16* __restrict__ wkf, _Float16* __restrict__ wgf,
          const float* __restrict__ sparse,
          const float* __restrict__ Wq, const float* __restrict__ sq, const float* __restrict__ bq,
          const float* __restrict__ Wv, const float* __restrict__ sv, const float* __restrict__ bv,
          float* __restrict__ outq, float* __restrict__ outv) {
    if (blockIdx.x < 512) {
        int idx = blockIdx.x * blockDim.x + threadIdx.x;   // 0..131071
        const float* src;
        _Float16* dst;
        int k;
        if (idx < 65536) { src = wk; dst = wkf; k = idx; }
        else             { src = wg; dst = wgf; k = idx - 65536; }
        f32x4 v = *reinterpret_cast<const f32x4*>(src + (size_t)k * 4);
        us4 o;
#pragma unroll
        for (int e = 0; e < 4; ++e) o[e] = f16bits(v[e]);
        *reinterpret_cast<us4*>(dst + (size_t)k * 4) = o;
        return;
    }

    const int bid = blockIdx.x - 512;            // 0..255
    const int bx = bid & 15, by = (bid >> 4) & 7, bz = bid >> 7;
    const float* W  = (bz == 0) ? Wq : Wv;
    const float* sc = (bz == 0) ? sq : sv;
    const float* bi = (bz == 0) ? bq : bv;
    float* orow     = (bz == 0) ? outq : outv;

    __shared__ float Wt[64][33];
    __shared__ float St[32][65];

    const int m0 = bx * 64;
    const int o0 = by * 64;
    const int t  = threadIdx.x;
    const int ty = t >> 4, tx = t & 15;

    float acc[4][4] = {};

    for (int k0 = 0; k0 < 512; k0 += 32) {
        {
            int ol = t >> 2, kl = (t & 3) * 8;
            const float* p = W + (size_t)(o0 + ol) * 512 + k0 + kl;
            f32x4 v0 = *reinterpret_cast<const f32x4*>(p);
            f32x4 v1 = *reinterpret_cast<const f32x4*>(p + 4);
#pragma unroll
            for (int e = 0; e < 4; ++e) { Wt[ol][kl + e] = v0[e]; Wt[ol][kl + 4 + e] = v1[e]; }
        }
        {
            int kl = t >> 3, ml = (t & 7) * 8;
            int mm = m0 + ml;
            int bb = mm >> 5, iidx = mm & 31;
            const float* p = sparse + (size_t)bb * 16384 + (size_t)(k0 + kl) * 32 + iidx;
            f32x4 v0 = *reinterpret_cast<const f32x4*>(p);
            f32x4 v1 = *reinterpret_cast<const f32x4*>(p + 4);
#pragma unroll
            for (int e = 0; e < 4; ++e) { St[kl][ml + e] = v0[e]; St[kl][ml + 4 + e] = v1[e]; }
        }
        __syncthreads();
#pragma unroll
        for (int kk = 0; kk < 32; ++kk) {
            float av[4], bvv[4];
#pragma unroll
            for (int e = 0; e < 4; ++e) av[e]  = Wt[ty * 4 + e][kk];
#pragma unroll
            for (int e = 0; e < 4; ++e) bvv[e] = St[kk][tx * 4 + e];
#pragma unroll
            for (int a = 0; a < 4; ++a)
#pragma unroll
                for (int bb2 = 0; bb2 < 4; ++bb2) acc[a][bb2] += av[a] * bvv[bb2];
        }
        __syncthreads();
    }
#pragma unroll
    for (int ae = 0; ae < 4; ++ae) {
        int o = o0 + ty * 4 + ae;
        float s = sc[o], bb2 = bi[o];
#pragma unroll
        for (int be = 0; be < 4; ++be) {
            int mm = m0 + tx * 4 + be;
            float h = acc[ae][be] * s + bb2;
            h = (h >= 0.f) ? h : 0.2f * h;
            orow[(size_t)mm * 512 + o] = h;
        }
    }
}

// ---------------------------------------------------------------------------
// Kernel C: fused main. One WG (16 waves, 1024 thr) per (b,i).
// Best-measured structure (R18): f16 MFMA; weight K-panels double-buffered in
// LDS via global_load_lds with m173 pre-swizzled source; barrier-free K-loops
// (WP rows wave-private, readiness via counted vmcnt(2)); depth-2 frag
// prefetch expressed at source level; race-fix barrier before epilogue1;
// two-pass softmax.
// ---------------------------------------------------------------------------
__global__ __launch_bounds__(1024, 4)
void fused_attn(const float* __restrict__ dense,
                const _Float16* __restrict__ wkf,
                const _Float16* __restrict__ wgf,
                const float* __restrict__ wsq,
                const float* __restrict__ wsv,
                const float* __restrict__ sk, const float* __restrict__ bk,
                const float* __restrict__ sg, const float* __restrict__ bg,
                float* __restrict__ out) {
    __shared__ __align__(16) _Float16 XH[64][520];     // 66.5 KB, X -> D (f16)
    __shared__ __align__(16) _Float16 WP[2][512 * 32]; // 2 x 32 KB weight panels
    __shared__ __align__(16) float qrow[512];
    __shared__ __align__(16) float vrow[512];
    __shared__ float wredA[16][64];
    __shared__ float wredB[16][64];

    const int m   = blockIdx.x;        // 0..1023
    const int b   = m >> 5, ii = m & 31;
    const int tid = threadIdx.x;       // 0..1023
    const int w   = tid >> 6;          // wave 0..15
    const int l   = tid & 63;
    const int l15 = l & 15;
    const int lk  = l >> 4;            // 0..3

    const int tsw = ((l & 3) - ((l >> 3) & 3)) & 3;   // m173 source swizzle
    const int orl = l >> 2;
    const int aslot = (lk + ((l15 >> 1) & 3)) & 3;

    // ---- prologue: DMA Wk panel 0 into WP[0] (overlaps X staging)
#pragma unroll
    for (int ih = 0; ih < 2; ++ih) {
        const int o = w * 32 + ih * 16 + orl;
        GLL(wkf + (size_t)o * 512 + tsw * 8, &WP[0][(w * 32 + ih * 16) * 32]);
    }

    if (tid < 512) qrow[tid] = wsq[(size_t)m * 512 + tid];
    else           vrow[tid - 512] = wsv[(size_t)m * 512 + (tid - 512)];

    {   // stage X (f16): thread owns j-row l, c-block [w*32, +32)
        const float* src = dense + (size_t)b * 512 * 2048 + (size_t)ii * 64 + l;
#pragma unroll
        for (int e8 = 0; e8 < 4; ++e8) {
            const int c0 = w * 32 + e8 * 8;
            us8 pk;
#pragma unroll
            for (int e = 0; e < 8; ++e)
                pk[e] = f16bits(src[(size_t)(c0 + e) * 2048]);
            *reinterpret_cast<us8*>(&XH[l][c0]) = pk;
        }
    }
    __syncthreads();   // full drain: X staged + panel 0 resident (vmcnt=0)

    f32x4 acc[2][4];
#pragma unroll
    for (int fm = 0; fm < 2; ++fm)
#pragma unroll
        for (int fn = 0; fn < 4; ++fn) acc[fm][fn] = (f32x4){0.f, 0.f, 0.f, 0.f};

    f16x8 af[2], bf[4], afn[2], bfn[4];

    // GEMM1 pipeline prologue: issue panel 1; read frags(0)
#pragma unroll
    for (int ih = 0; ih < 2; ++ih) {
        const int o = w * 32 + ih * 16 + orl;
        GLL(wkf + (size_t)o * 512 + 32 + tsw * 8, &WP[1][(w * 32 + ih * 16) * 32]);
    }
#pragma unroll
    for (int fm = 0; fm < 2; ++fm)
        af[fm] = *reinterpret_cast<const f16x8*>(
            &WP[0][(w * 32 + fm * 16 + l15) * 32 + aslot * 8]);
#pragma unroll
    for (int fn = 0; fn < 4; ++fn)
        bf[fn] = *reinterpret_cast<const f16x8*>(&XH[fn * 16 + l15][lk * 8]);

    // ---- GEMM1: dn_k[o,j] = sum_c Wk[o,c] * X[c,j]
    for (int ks = 0; ks < 16; ++ks) {
        asm volatile("s_waitcnt lgkmcnt(0)" ::: "memory");  // frags(ks) ready
        {   // issue panel ks+2 into WP[ks&1] (14->wgf p0, 15->wgf p1)
            const _Float16* nxt = (ks <= 13) ? (wkf + (size_t)(ks + 2) * 32)
                                : (ks == 14) ? wgf : (wgf + 32);
#pragma unroll
            for (int ih = 0; ih < 2; ++ih) {
                const int o = w * 32 + ih * 16 + orl;
                GLL(nxt + (size_t)o * 512 + tsw * 8, &WP[ks & 1][(w * 32 + ih * 16) * 32]);
            }
        }
        asm volatile("s_waitcnt vmcnt(2)" ::: "memory");    // panel ks+1 landed
        {   // read frags(ks+1): af always (ks=15 -> wgf p0 = GEMM2 af(0))
            const _Float16* pbuf = WP[(ks + 1) & 1];
#pragma unroll
            for (int fm = 0; fm < 2; ++fm)
                afn[fm] = *reinterpret_cast<const f16x8*>(
                    pbuf + (w * 32 + fm * 16 + l15) * 32 + aslot * 8);
            if (ks < 15) {
#pragma unroll
                for (int fn = 0; fn < 4; ++fn)
                    bfn[fn] = *reinterpret_cast<const f16x8*>(
                        &XH[fn * 16 + l15][(ks + 1) * 32 + lk * 8]);
            }
        }
        __builtin_amdgcn_s_setprio(1);
#pragma unroll
        for (int fm = 0; fm < 2; ++fm)
#pragma unroll
            for (int fn = 0; fn < 4; ++fn)
                acc[fm][fn] = __builtin_amdgcn_mfma_f32_16x16x32_f16(af[fm], bf[fn], acc[fm][fn], 0, 0, 0);
        __builtin_amdgcn_s_setprio(0);
#pragma unroll
        for (int fm = 0; fm < 2; ++fm) af[fm] = afn[fm];
#pragma unroll
        for (int fn = 0; fn < 4; ++fn) bf[fn] = bfn[fn];
    }
    // af[] now holds GEMM2's af(0) (wgf panel 0, resident in WP[0])

    // RACE FIX: all waves done reading X from XH before D overwrites it
    asm volatile("s_waitcnt lgkmcnt(0)" ::: "memory");
    SBAR();

    // ---- epilogue1: d = q - lrelu(acc*sk+bk), f16, write D over XH
#pragma unroll
    for (int fm = 0; fm < 2; ++fm) {
        const int o0 = w * 32 + fm * 16 + lk * 4;
        f32x4 skv = *reinterpret_cast<const f32x4*>(sk + o0);
        f32x4 bkv = *reinterpret_cast<const f32x4*>(bk + o0);
        f32x4 qv4 = *reinterpret_cast<const f32x4*>(&qrow[o0]);
#pragma unroll
        for (int fn = 0; fn < 4; ++fn) {
            const int j = fn * 16 + l15;
            us4 pkh;
#pragma unroll
            for (int r = 0; r < 4; ++r) {
                float h = acc[fm][fn][r] * skv[r] + bkv[r];
                h = (h >= 0.f) ? h : 0.2f * h;
                pkh[r] = f16bits(qv4[r] - h);
            }
            *reinterpret_cast<us4*>(&XH[j][o0]) = pkh;
        }
    }
    asm volatile("s_waitcnt lgkmcnt(0)" ::: "memory");
    SBAR();   // D visible to all waves (wgf p1 DMA still in flight - OK)

    // ---- GEMM2: g[oo,j] = sum_o Wg[oo,o] * d[o,j]
#pragma unroll
    for (int fm = 0; fm < 2; ++fm)
#pragma unroll
        for (int fn = 0; fn < 4; ++fn) acc[fm][fn] = (f32x4){0.f, 0.f, 0.f, 0.f};

    // GEMM2 pipeline prologue: bf(0) from D (af(0) already in regs)
#pragma unroll
    for (int fn = 0; fn < 4; ++fn)
        bf[fn] = *reinterpret_cast<const f16x8*>(&XH[fn * 16 + l15][lk * 8]);

    for (int g = 0; g < 16; ++g) {
        asm volatile("s_waitcnt lgkmcnt(0)" ::: "memory");
        if (g <= 13) {   // issue wgf panel g+2 into WP[g&1]
            const _Float16* nxt = wgf + (size_t)(g + 2) * 32;
#pragma unroll
            for (int ih = 0; ih < 2; ++ih) {
                const int o = w * 32 + ih * 16 + orl;
                GLL(nxt + (size_t)o * 512 + tsw * 8, &WP[g & 1][(w * 32 + ih * 16) * 32]);
            }
            asm volatile("s_waitcnt vmcnt(2)" ::: "memory");   // panel g+1 landed
        } else {
            asm volatile("s_waitcnt vmcnt(0)" ::: "memory");
        }
        if (g < 15) {
            const _Float16* pbuf = WP[(g + 1) & 1];
#pragma unroll
            for (int fm = 0; fm < 2; ++fm)
                afn[fm] = *reinterpret_cast<const f16x8*>(
                    pbuf + (w * 32 + fm * 16 + l15) * 32 + aslot * 8);
#pragma unroll
            for (int fn = 0; fn < 4; ++fn)
                bfn[fn] = *reinterpret_cast<const f16x8*>(
                    &XH[fn * 16 + l15][(g + 1) * 32 + lk * 8]);
        }
        __builtin_amdgcn_s_setprio(1);
#pragma unroll
        for (int fm = 0; fm < 2; ++fm)
#pragma unroll
            for (int fn = 0; fn < 4; ++fn)
                acc[fm][fn] = __builtin_amdgcn_mfma_f32_16x16x32_f16(af[fm], bf[fn], acc[fm][fn], 0, 0, 0);
        __builtin_amdgcn_s_setprio(0);
        if (g < 15) {
#pragma unroll
            for (int fm = 0; fm < 2; ++fm) af[fm] = afn[fm];
#pragma unroll
            for (int fn = 0; fn < 4; ++fn) bf[fn] = bfn[fn];
        }
    }

    // ---- epilogue2 in place: g = lrelu(acc*sg+bg)
#pragma unroll
    for (int fm = 0; fm < 2; ++fm) {
        const int o0 = w * 32 + fm * 16 + lk * 4;
        f32x4 sgv = *reinterpret_cast<const f32x4*>(sg + o0);
        f32x4 bgv = *reinterpret_cast<const f32x4*>(bg + o0);
#pragma unroll
        for (int fn = 0; fn < 4; ++fn)
#pragma unroll
            for (int r = 0; r < 4; ++r) {
                float h = acc[fm][fn][r] * sgv[r] + bgv[r];
                acc[fm][fn][r] = (h >= 0.f) ? h : 0.2f * h;
            }
    }

    // ---- softmax over the 512 channels, per j column (two-pass)
    float pm[4];
#pragma unroll
    for (int fn = 0; fn < 4; ++fn) {
        float mx = -1e30f;
#pragma unroll
        for (int fm = 0; fm < 2; ++fm)
#pragma unroll
            for (int r = 0; r < 4; ++r) mx = fmaxf(mx, acc[fm][fn][r]);
        mx = fmaxf(mx, __shfl_xor(mx, 16, 64));
        mx = fmaxf(mx, __shfl_xor(mx, 32, 64));
        pm[fn] = mx;
    }
    if (l < 16) {
#pragma unroll
        for (int fn = 0; fn < 4; ++fn) wredA[w][fn * 16 + l] = pm[fn];
    }
    __syncthreads();

    float jmax[4];
#pragma unroll
    for (int fn = 0; fn < 4; ++fn) {
        float mx = wredA[0][fn * 16 + l15];
#pragma unroll
        for (int ww = 1; ww < 16; ++ww) mx = fmaxf(mx, wredA[ww][fn * 16 + l15]);
        jmax[fn] = mx;
    }

    float ps[4] = {0.f, 0.f, 0.f, 0.f};
#pragma unroll
    for (int fm = 0; fm < 2; ++fm)
#pragma unroll
        for (int fn = 0; fn < 4; ++fn)
#pragma unroll
            for (int r = 0; r < 4; ++r) {
                float e = __expf(acc[fm][fn][r] - jmax[fn]);
                acc[fm][fn][r] = e;
                ps[fn] += e;
            }
#pragma unroll
    for (int fn = 0; fn < 4; ++fn) {
        ps[fn] += __shfl_xor(ps[fn], 16, 64);
        ps[fn] += __shfl_xor(ps[fn], 32, 64);
    }
    if (l < 16) {
#pragma unroll
        for (int fn = 0; fn < 4; ++fn) wredB[w][fn * 16 + l] = ps[fn];
    }
    __syncthreads();

    float rinv[4];
#pragma unroll
    for (int fn = 0; fn < 4; ++fn) {
        float s = 0.f;
#pragma unroll
        for (int ww = 0; ww < 16; ++ww) s += wredB[ww][fn * 16 + l15];
        rinv[fn] = 1.f / s;
    }

    // ---- out[b,oo,i] = sp_v[oo] * sum_j coef[oo,j]   (FP32 store)
#pragma unroll
    for (int fm = 0; fm < 2; ++fm) {
#pragma unroll
        for (int r = 0; r < 4; ++r) {
            float tsum = 0.f;
#pragma unroll
            for (int fn = 0; fn < 4; ++fn) tsum += acc[fm][fn][r] * rinv[fn];
            tsum += __shfl_xor(tsum, 1, 64);
            tsum += __shfl_xor(tsum, 2, 64);
            tsum += __shfl_xor(tsum, 4, 64);
            tsum += __shfl_xor(tsum, 8, 64);
            if (l15 == 0) {
                int oo = w * 32 + fm * 16 + lk * 4 + r;
                out[((size_t)b * 512 + oo) * 32 + ii] = vrow[oo] * tsum;
            }
        }
    }
}

// ---------------------------------------------------------------------------
extern "C" void kernel_launch(void* const* d_in, const int* in_sizes, int n_in,
                              void* d_out, int out_size, void* d_ws, size_t ws_size,
                              hipStream_t stream) {
    const float* sparse = (const float*)d_in[0];
    const float* dense  = (const float*)d_in[1];
    const float* Wq = (const float*)d_in[2];
    const float* sq = (const float*)d_in[3];
    const float* bq = (const float*)d_in[4];
    const float* Wk = (const float*)d_in[5];
    const float* sk = (const float*)d_in[6];
    const float* bk = (const float*)d_in[7];
    const float* Wv = (const float*)d_in[8];
    const float* sv = (const float*)d_in[9];
    const float* bv = (const float*)d_in[10];
    const float* Wg = (const float*)d_in[11];
    const float* sg = (const float*)d_in[12];
    const float* bg = (const float*)d_in[13];
    float* out = (float*)d_out;

    // workspace: [sp_q f32 2MB][sp_v f32 2MB][Wk f16 512KB][Wg f16 512KB]
    float* wsq = (float*)d_ws;
    float* wsv = wsq + 1024 * 512;
    _Float16* wkf = (_Float16*)(wsv + 1024 * 512);
    _Float16* wgf = wkf + 512 * 512;

    prep<<<768, 256, 0, stream>>>(Wk, Wg, wkf, wgf,
                                  sparse, Wq, sq, bq, Wv, sv, bv, wsq, wsv);
    fused_attn<<<1024, 1024, 0, stream>>>(dense, wkf, wgf, wsq, wsv, sk, bk, sg, bg, out);
}